// Round 2
// baseline (459.461 us; speedup 1.0000x reference)
//
#include <hip/hip_runtime.h>

#define EMB   256
#define HID   128
#define RELD  64
#define NREL  10
#define TE    128

typedef __attribute__((ext_vector_type(8)))  short bf16x8;
typedef __attribute__((ext_vector_type(16))) float f32x16;

__device__ __forceinline__ float bf16_to_f32(unsigned short u) {
    union { unsigned int i; float f; } v;
    v.i = ((unsigned int)u) << 16;
    return v.f;
}

__device__ __forceinline__ unsigned short f32_to_bf16(float x) {
    union { unsigned int i; float f; } v;
    v.f = x;
    unsigned int b = v.i;
    unsigned int rounded = b + 0x7fffu + ((b >> 16) & 1u);   // round-nearest-even
    return (unsigned short)(rounded >> 16);
}

template <bool F32>
__device__ __forceinline__ float ldx(const void* p, size_t i) {
    if (F32) return ((const float*)p)[i];
    return bf16_to_f32(((const unsigned short*)p)[i]);
}

// In-kernel parallel dtype detect (validated rounds 7-12: fp32 inputs -> true).
__device__ __forceinline__ bool detect_f32(const void* nodeEmb) {
    const float* f = (const float*)nodeEmb;
    float x = f[(threadIdx.x & 63) * 997];
    bool sane = isfinite(x) && fabsf(x) < 1.0e6f;
    unsigned long long m = __ballot(sane);
    return __popcll(m) >= 48;
}

// Register-free async global->LDS (16B per lane). LDS dest must be the
// wave-uniform base; HW adds lane*16.
__device__ __forceinline__ void gload16(const void* g, void* l) {
    __builtin_amdgcn_global_load_lds(
        (const __attribute__((address_space(1))) unsigned int*)g,
        (__attribute__((address_space(3))) unsigned int*)l, 16, 0, 0);
}

// ---------------------------------------------------------------------------
// Merged prep kernel (UNCHANGED):
//   blocks [0, convBlocks)    : fp32 node table -> bf16 copy
//   blocks [convBlocks, +448) : weights -> bf16 in MFMA-FRAGMENT ORDER: per
//                               K-chunk (32 k), 512 16-B units, unit g holds
//                               W[kc*32 + (g>>7)*8 .. +7][g&127].
//   block  convBlocks+448     : per-relation Q table (10x128 fp32)
// ---------------------------------------------------------------------------
template <bool F32>
__device__ void prep_body(int vb, const void* W_edge, const void* W_k,
                          const void* W_v, const void* W_o1, const void* rel_emb,
                          const void* W_q, const void* b_q,
                          unsigned short* WTe, unsigned short* WTk,
                          unsigned short* WTv, unsigned short* WTo1, float* Qtab)
{
    if (vb < 448) {
        int idx = vb * 256 + threadIdx.x;             // 0 .. 114687
        if (idx < 65536) {                            // W_edge: 16 chunks x 4096
            int kc = idx >> 12, e = idx & 4095;
            int g = e >> 3, j = e & 7;
            int col = g & 127, kg = g >> 7;
            int k = kc * 32 + kg * 8 + j;
            WTe[idx] = f32_to_bf16(ldx<F32>(W_edge, (size_t)k * HID + col));
        } else if (idx < 65536 + 16384) {             // W_k: 4 chunks x 4096
            int i = idx - 65536;
            int kc = i >> 12, e = i & 4095;
            int g = e >> 3, j = e & 7;
            int col = g & 127, kg = (g >> 7) & 3;
            int k = kc * 32 + kg * 8 + j;
            WTk[i] = f32_to_bf16(ldx<F32>(W_k, (size_t)k * HID + col));
        } else if (idx < 65536 + 2 * 16384) {
            int i = idx - 65536 - 16384;
            int kc = i >> 12, e = i & 4095;
            int g = e >> 3, j = e & 7;
            int col = g & 127, kg = (g >> 7) & 3;
            int k = kc * 32 + kg * 8 + j;
            WTv[i] = f32_to_bf16(ldx<F32>(W_v, (size_t)k * HID + col));
        } else {
            int i = idx - 65536 - 2 * 16384;
            int kc = i >> 12, e = i & 4095;
            int g = e >> 3, j = e & 7;
            int col = g & 127, kg = (g >> 7) & 3;
            int k = kc * 32 + kg * 8 + j;
            WTo1[i] = f32_to_bf16(ldx<F32>(W_o1, (size_t)k * HID + col));
        }
    } else {
        const int t = threadIdx.x;
        const int c = t & (HID - 1);
        const int h = t >> 7;
        for (int r = h; r < NREL; r += 2) {
            float acc = 0.f;
            for (int d = 0; d < RELD; ++d)
                acc += ldx<F32>(rel_emb, r * RELD + d) * ldx<F32>(W_q, (size_t)d * HID + c);
            Qtab[r * HID + c] = acc + ldx<F32>(b_q, c);
        }
    }
}

__global__ void prep_kernel(const void* nodeEmb,
                            const void* W_edge, const void* W_k, const void* W_v,
                            const void* W_o1, const void* rel_emb, const void* W_q,
                            const void* b_q,
                            unsigned short* WTe, unsigned short* WTk,
                            unsigned short* WTv, unsigned short* WTo1, float* Qtab,
                            unsigned short* nodeBf16, int convBlocks,
                            unsigned long long nodeElems)
{
    bool f32 = detect_f32(nodeEmb);
    int b = blockIdx.x;
    if (b < convBlocks) {
        if (!f32) return;                             // bf16 input: no conversion
        unsigned long long i = (unsigned long long)b * 2048ull + threadIdx.x * 8;
        if (i + 8 <= nodeElems) {
            const float* src = (const float*)nodeEmb + i;
            float4 f0 = *(const float4*)src;
            float4 f1 = *(const float4*)(src + 4);
            union { unsigned short us[8]; uint4 v; } pk;
            pk.us[0] = f32_to_bf16(f0.x); pk.us[1] = f32_to_bf16(f0.y);
            pk.us[2] = f32_to_bf16(f0.z); pk.us[3] = f32_to_bf16(f0.w);
            pk.us[4] = f32_to_bf16(f1.x); pk.us[5] = f32_to_bf16(f1.y);
            pk.us[6] = f32_to_bf16(f1.z); pk.us[7] = f32_to_bf16(f1.w);
            *(uint4*)(nodeBf16 + i) = pk.v;
        }
        return;
    }
    b -= convBlocks;
    if (f32) prep_body<true >(b, W_edge, W_k, W_v, W_o1, rel_emb, W_q, b_q,
                              WTe, WTk, WTv, WTo1, Qtab);
    else     prep_body<false>(b, W_edge, W_k, W_v, W_o1, rel_emb, W_q, b_q,
                              WTe, WTk, WTv, WTo1, Qtab);
}

// ---------------------------------------------------------------------------
// Shared memory, 78 KB -> 2 blocks/CU (16 waves). All MFMA-side tiles are in
// FRAGMENT ORDER (unit u = 16B):
//   SA chunk:  u = s*256 + h5*128 + row       (A, 128 rows x 32 k)
//   SB chunk:  u = (s*2+h5)*128 + col         (B, 32 k x 128 cols, = WT layout)
//   sHid:      u = kg*128 + row, kg = k>>3    (128 rows x 128 k)
// so global_load_lds's linear lane->LDS mapping AND the ds_read_b128 fragment
// reads are both conflict-free without swizzles.
// ---------------------------------------------------------------------------
struct __align__(16) Smem {
    unsigned short sHid[16 * 128 * 8];   // 32768 B
    unsigned short SA[2][4096];          // 16384 B: double-buffered A chunk
    unsigned short SB[2][4096];          // 16384 B: double-buffered B chunk
    float sQf[NREL * HID];               // 5120 B
    float sBias[5 * HID];                // 2560 B: b_edge|b_k|b_v|b_o1|W_o2
    float sSc[TE][4];                    // 2048 B
    float sAttn[TE][4];                  // 2048 B
    float sPart[TE][2];                  // 1024 B
    int   sSrc[TE], sTgt[TE], sRel[TE];  // 1536 B
};                                       // total 79872 B

// sHid element address (row, k) -> short index
__device__ __forceinline__ int shid_idx(int row, int k) {
    return (((k >> 3) * 128 + row) << 3) + (k & 7);
}

// ---------------------------------------------------------------------------
// Fused pipeline, 32x32x16 MFMA. Block = 128 edges, 512 threads = 8 waves.
// Wave w: rt=w>>1 (rows 32rt..+31), cg2=w&1 (cols 64cg2..+63).
//   A-frag: lane l -> A[m = l&31][k = (l>>5)*8 + j]
//   B-frag: lane l -> B[k = (l>>5)*8 + j][n = l&31]
//   C/D:    lane l, reg r -> row = (r&3) + 8*(r>>2) + 4*(l>>5), col = l&31
// Staging: per 32-k chunk, 512 threads each issue ONE register-free
// global_load_lds (8 KB A + 8 KB B per chunk in flight), double-buffered,
// one barrier per chunk (2-phase pipeline). Weights and gathered rows are
// each read from global exactly ONCE per block.
// ---------------------------------------------------------------------------
template <bool F32, bool GBF16>
__device__ void fused_body(
    Smem& sm,
    const void* gsrc, const int* edgeIdx, const int* relType,
    const unsigned short* WTe, const unsigned short* WTk,
    const unsigned short* WTv, const unsigned short* WTo1,
    const void* b_edge, const void* b_k, const void* b_v,
    const void* b_o1, const void* W_o2, const void* b_o2,
    const float* Qtab, void* outp, int E)
{
    const int t   = threadIdx.x;
    const int l   = t & 63;
    const int w   = t >> 6;          // 0..7
    const int c   = l & 31;
    const int h5  = l >> 5;
    const int rt  = w >> 1;          // 0..3  row tile
    const int cg2 = w & 1;           // 0..1  col tile
    const int bs  = blockIdx.x * TE;
    const int aRow = 32 * rt + c;

    // ---- preamble ----
    if (t < TE) {
        int e = bs + t;
        if (e >= E) e = E - 1;
        if (e < 0)  e = 0;
        sm.sSrc[t] = edgeIdx[e];
        sm.sTgt[t] = edgeIdx[E + e];
        int r = relType[e];
        if (r < 0) r = 0;
        if (r >= NREL) r = NREL - 1;
        sm.sRel[t] = r;
    }
    for (int i = t; i < 5 * HID; i += 512) {
        int which = i >> 7, j = i & (HID - 1);
        float v = (which == 0) ? ldx<F32>(b_edge, j)
                : (which == 1) ? ldx<F32>(b_k, j)
                : (which == 2) ? ldx<F32>(b_v, j)
                : (which == 3) ? ldx<F32>(b_o1, j)
                               : ldx<F32>(W_o2, j);
        sm.sBias[i] = v;
    }
    for (int i = t; i < NREL * HID; i += 512)
        sm.sQf[i] = Qtab[i];
    __syncthreads();

    // staging role of this thread: unit t = (s, h5, row)
    const int    stS   = t >> 8;          // 0..1
    const int    stH5  = (t >> 7) & 1;
    const int    stRow = t & 127;
    const size_t rowOffS = (size_t)sm.sSrc[stRow] * EMB;
    const size_t rowOffT = (size_t)sm.sTgt[stRow] * EMB;
    const int    colSub  = stS * 16 + stH5 * 8;     // element offset in 32-chunk
    char* const  ldsWaveA0 = (char*)sm.SA[0] + w * 1024;
    char* const  ldsWaveA1 = (char*)sm.SA[1] + w * 1024;
    char* const  ldsWaveB0 = (char*)sm.SB[0] + w * 1024;
    char* const  ldsWaveB1 = (char*)sm.SB[1] + w * 1024;

    #define STAGE_A(kc, buf)                                                     \
    {                                                                            \
        size_t eoff = (((kc) < 8) ? rowOffS : rowOffT)                           \
                      + (size_t)(((kc) & 7) * 32 + colSub);                      \
        if (GBF16) {                                                             \
            gload16((const unsigned short*)gsrc + eoff,                          \
                    (buf) ? ldsWaveA1 : ldsWaveA0);                              \
        } else {                                                                 \
            const float* p_ = (const float*)gsrc + eoff;                         \
            float4 f0_ = *(const float4*)p_;                                     \
            float4 f1_ = *(const float4*)(p_ + 4);                               \
            union { unsigned short us[8]; uint4 v; } pk_;                        \
            pk_.us[0] = f32_to_bf16(f0_.x); pk_.us[1] = f32_to_bf16(f0_.y);      \
            pk_.us[2] = f32_to_bf16(f0_.z); pk_.us[3] = f32_to_bf16(f0_.w);      \
            pk_.us[4] = f32_to_bf16(f1_.x); pk_.us[5] = f32_to_bf16(f1_.y);      \
            pk_.us[6] = f32_to_bf16(f1_.z); pk_.us[7] = f32_to_bf16(f1_.w);      \
            *(uint4*)((char*)sm.SA[(buf)] + t * 16) = pk_.v;                     \
        }                                                                        \
    }

    #define STAGE_B(WT, kc, buf)                                                 \
        gload16((WT) + (kc) * 4096 + t * 8, (buf) ? ldsWaveB1 : ldsWaveB0);

    // MFMA on one staged chunk: A from SA[buf], B from SB[buf]
    #define MFMA_SA(buf, accv)                                                   \
    {                                                                            \
        const char* sa_ = (const char*)sm.SA[(buf)];                             \
        const char* sb_ = (const char*)sm.SB[(buf)];                             \
        _Pragma("unroll")                                                        \
        for (int s_ = 0; s_ < 2; ++s_) {                                         \
            bf16x8 a_ = *(const bf16x8*)(sa_ + ((s_ * 256 + h5 * 128 + aRow) << 4)); \
            _Pragma("unroll")                                                    \
            for (int ct_ = 0; ct_ < 2; ++ct_) {                                  \
                bf16x8 b_ = *(const bf16x8*)                                     \
                    (sb_ + ((s_ * 256 + h5 * 128 + 64 * cg2 + 32 * ct_ + c) << 4)); \
                accv[ct_] = __builtin_amdgcn_mfma_f32_32x32x16_bf16(             \
                                a_, b_, accv[ct_], 0, 0, 0);                     \
            }                                                                    \
        }                                                                        \
    }

    // MFMA with A from sHid (fragment order), B from SB[buf]
    #define MFMA_H(kc, buf, accv)                                                \
    {                                                                            \
        const char* sb_ = (const char*)sm.SB[(buf)];                             \
        _Pragma("unroll")                                                        \
        for (int s_ = 0; s_ < 2; ++s_) {                                         \
            bf16x8 a_ = *(const bf16x8*)((const char*)sm.sHid +                  \
                         ((((kc) * 4 + s_ * 2 + h5) * 128 + aRow) << 4));        \
            _Pragma("unroll")                                                    \
            for (int ct_ = 0; ct_ < 2; ++ct_) {                                  \
                bf16x8 b_ = *(const bf16x8*)                                     \
                    (sb_ + ((s_ * 256 + h5 * 128 + 64 * cg2 + 32 * ct_ + c) << 4)); \
                accv[ct_] = __builtin_amdgcn_mfma_f32_32x32x16_bf16(             \
                                a_, b_, accv[ct_], 0, 0, 0);                     \
            }                                                                    \
        }                                                                        \
    }

    // ---- GEMM1: hid = relu([src|tgt] @ W_edge + b_edge), K=512, 16 chunks ----
    f32x16 acc[2];
    acc[0] = (f32x16)(0.0f); acc[1] = (f32x16)(0.0f);
    STAGE_A(0, 0); STAGE_B(WTe, 0, 0);
    __syncthreads();                     // chunk 0 staged (vmcnt drained)
    #pragma unroll
    for (int kc = 0; kc < 16; ++kc) {
        int buf = kc & 1;
        if (kc < 15) { STAGE_A(kc + 1, buf ^ 1); STAGE_B(WTe, kc + 1, buf ^ 1); }
        MFMA_SA(buf, acc);
        __syncthreads();                 // next chunk staged; buf consumed
    }
    {   // epilogue: + b_edge, relu -> sHid (bf16, fragment order)
        #pragma unroll
        for (int ct = 0; ct < 2; ++ct) {
            int col = 64 * cg2 + 32 * ct + c;
            float bb = sm.sBias[col];
            #pragma unroll
            for (int r = 0; r < 16; ++r) {
                int erow = 32 * rt + (r & 3) + 8 * (r >> 2) + 4 * h5;
                sm.sHid[shid_idx(erow, col)] = f32_to_bf16(fmaxf(acc[ct][r] + bb, 0.f));
            }
        }
    }

    // ---- K GEMM: K=128, 4 chunks, A resident in sHid ----
    f32x16 kacc[2];
    kacc[0] = (f32x16)(0.0f); kacc[1] = (f32x16)(0.0f);
    STAGE_B(WTk, 0, 0);
    __syncthreads();                     // sHid visible + chunk 0 staged
    #pragma unroll
    for (int kc = 0; kc < 4; ++kc) {
        int buf = kc & 1;
        if (kc < 3) STAGE_B(WTk, kc + 1, buf ^ 1);
        MFMA_H(kc, buf, kacc);
        __syncthreads();
    }

    // ---- scores[e][h] = sum_col Q[rel][col]*(K+bk)[e][col] / sqrt(32) ----
    {
        float ps[2][16];
        #pragma unroll
        for (int ct = 0; ct < 2; ++ct) {
            int col = 64 * cg2 + 32 * ct + c;
            float bk = sm.sBias[HID + col];
            #pragma unroll
            for (int r = 0; r < 16; ++r) {
                int erow = 32 * rt + (r & 3) + 8 * (r >> 2) + 4 * h5;
                ps[ct][r] = (kacc[ct][r] + bk) * sm.sQf[sm.sRel[erow] * HID + col];
            }
        }
        #pragma unroll
        for (int m = 1; m < 32; m <<= 1)
            #pragma unroll
            for (int ct = 0; ct < 2; ++ct)
                #pragma unroll
                for (int r = 0; r < 16; ++r)
                    ps[ct][r] += __shfl_xor(ps[ct][r], m, 64);
        if (c == 0) {
            const float inv = 0.17677669529663687f;   // 1/sqrt(32)
            #pragma unroll
            for (int ct = 0; ct < 2; ++ct) {
                int head = 2 * cg2 + ct;
                #pragma unroll
                for (int r = 0; r < 16; ++r) {
                    int erow = 32 * rt + (r & 3) + 8 * (r >> 2) + 4 * h5;
                    sm.sSc[erow][head] = ps[ct][r] * inv;
                }
            }
        }
    }
    __syncthreads();
    if (t < TE) {   // softmax over 4 heads
        float s0 = sm.sSc[t][0], s1 = sm.sSc[t][1];
        float s2 = sm.sSc[t][2], s3 = sm.sSc[t][3];
        float m = fmaxf(fmaxf(s0, s1), fmaxf(s2, s3));
        float e0 = expf(s0 - m), e1 = expf(s1 - m);
        float e2 = expf(s2 - m), e3 = expf(s3 - m);
        float den = e0 + e1 + e2 + e3;
        sm.sAttn[t][0] = e0 / den; sm.sAttn[t][1] = e1 / den;
        sm.sAttn[t][2] = e2 / den; sm.sAttn[t][3] = e3 / den;
    }
    __syncthreads();

    // ---- V GEMM ----
    f32x16 vacc[2];
    vacc[0] = (f32x16)(0.0f); vacc[1] = (f32x16)(0.0f);
    STAGE_B(WTv, 0, 0);
    __syncthreads();
    #pragma unroll
    for (int kc = 0; kc < 4; ++kc) {
        int buf = kc & 1;
        if (kc < 3) STAGE_B(WTv, kc + 1, buf ^ 1);
        MFMA_H(kc, buf, vacc);
        __syncthreads();                 // final iter: fences all sHid A-reads
    }

    // ---- attend + residual (in-place on sHid; element-owner = this lane) ----
    {
        #pragma unroll
        for (int ct = 0; ct < 2; ++ct) {
            int col  = 64 * cg2 + 32 * ct + c;
            int head = 2 * cg2 + ct;
            float bv = sm.sBias[2 * HID + col];
            #pragma unroll
            for (int r = 0; r < 16; ++r) {
                int erow = 32 * rt + (r & 3) + 8 * (r >> 2) + 4 * h5;
                float at = sm.sAttn[erow][head];
                int   si = shid_idx(erow, col);
                float hv = bf16_to_f32(sm.sHid[si]);
                sm.sHid[si] = f32_to_bf16(at * (vacc[ct][r] + bv) + hv);
            }
        }
    }
    __syncthreads();                     // sHid updated for all waves

    // ---- GEMM3 + final dot with W_o2 ----
    f32x16 oacc[2];
    oacc[0] = (f32x16)(0.0f); oacc[1] = (f32x16)(0.0f);
    STAGE_B(WTo1, 0, 0);
    __syncthreads();
    #pragma unroll
    for (int kc = 0; kc < 4; ++kc) {
        int buf = kc & 1;
        if (kc < 3) STAGE_B(WTo1, kc + 1, buf ^ 1);
        MFMA_H(kc, buf, oacc);
        __syncthreads();
    }
    {
        float pr[16];
        #pragma unroll
        for (int r = 0; r < 16; ++r) pr[r] = 0.f;
        #pragma unroll
        for (int ct = 0; ct < 2; ++ct) {
            int col = 64 * cg2 + 32 * ct + c;
            float bo = sm.sBias[3 * HID + col];
            float wo = sm.sBias[4 * HID + col];
            #pragma unroll
            for (int r = 0; r < 16; ++r)
                pr[r] += fmaxf(oacc[ct][r] + bo, 0.f) * wo;
        }
        #pragma unroll
        for (int m = 1; m < 32; m <<= 1)
            #pragma unroll
            for (int r = 0; r < 16; ++r)
                pr[r] += __shfl_xor(pr[r], m, 64);
        if (c == 0) {
            #pragma unroll
            for (int r = 0; r < 16; ++r) {
                int erow = 32 * rt + (r & 3) + 8 * (r >> 2) + 4 * h5;
                sm.sPart[erow][cg2] = pr[r];
            }
        }
    }
    __syncthreads();
    if (t < TE) {
        int ge = bs + t;
        if (ge < E) {
            float val = sm.sPart[t][0] + sm.sPart[t][1] + ldx<F32>(b_o2, 0);
            // F32 path writes fp32 (round-10 lesson: output buffer is fp32).
            if (F32) ((float*)outp)[ge] = val;
            else     ((unsigned short*)outp)[ge] = f32_to_bf16(val);
        }
    }

    #undef STAGE_A
    #undef STAGE_B
    #undef MFMA_SA
    #undef MFMA_H
}

__global__ __launch_bounds__(512, 4) void RelationAttentionMLPHead_10539849744626_kernel(
    const void* nodeEmb, const unsigned short* nodeBf16, int useConv,
    const int* edgeIdx, const int* relType,
    const unsigned short* WTe, const unsigned short* WTk,
    const unsigned short* WTv, const unsigned short* WTo1,
    const void* b_edge, const void* b_k, const void* b_v,
    const void* b_o1, const void* W_o2, const void* b_o2,
    const float* Qtab, void* outp, int E)
{
    __shared__ Smem sm;     // single allocation shared by all instantiations
    if (detect_f32(nodeEmb)) {
        if (useConv)
            fused_body<true, true >(sm, nodeBf16, edgeIdx, relType, WTe, WTk, WTv, WTo1,
                                    b_edge, b_k, b_v, b_o1, W_o2, b_o2, Qtab, outp, E);
        else
            fused_body<true, false>(sm, nodeEmb, edgeIdx, relType, WTe, WTk, WTv, WTo1,
                                    b_edge, b_k, b_v, b_o1, W_o2, b_o2, Qtab, outp, E);
    } else {
        // input already bf16: gather straight from the input table
        fused_body<false, true>(sm, nodeEmb, edgeIdx, relType, WTe, WTk, WTv, WTo1,
                                b_edge, b_k, b_v, b_o1, W_o2, b_o2, Qtab, outp, E);
    }
}

extern "C" void kernel_launch(void* const* d_in, const int* in_sizes, int n_in,
                              void* d_out, int out_size, void* d_ws, size_t ws_size,
                              hipStream_t stream) {
    (void)n_in;

    const void* nodeEmb = d_in[0];
    const int*  edgeIdx = (const int*)d_in[1];
    const int*  relType = (const int*)d_in[2];
    const void* rel_emb = d_in[3];
    const void* W_edge  = d_in[4];
    const void* b_edge  = d_in[5];
    const void* W_q     = d_in[6];
    const void* b_q     = d_in[7];
    const void* W_k     = d_in[8];
    const void* b_k     = d_in[9];
    const void* W_v     = d_in[10];
    const void* b_v     = d_in[11];
    const void* W_o1    = d_in[12];
    const void* b_o1    = d_in[13];
    const void* W_o2    = d_in[14];
    const void* b_o2    = d_in[15];

    int E = out_size;
    if (E <= 0) E = in_sizes ? in_sizes[2] : 0;
    if (E <= 0) E = 500000;

    unsigned long long nodeElems =
        (in_sizes && in_sizes[0] > 0) ? (unsigned long long)in_sizes[0] : 25600000ull;

    // d_ws layout (recomputed every launch; graph-safe)
    char* ws = (char*)d_ws;
    float*          Qtab     = (float*)ws;                      // 5120 B
    unsigned short* WTe      = (unsigned short*)(ws + 8192);    // 131072 B
    unsigned short* WTk      = (unsigned short*)(ws + 139264);  // 32768 B
    unsigned short* WTv      = (unsigned short*)(ws + 172032);  // 32768 B
    unsigned short* WTo1     = (unsigned short*)(ws + 204800);  // 32768 B
    unsigned short* nodeBf16 = (unsigned short*)(ws + 237568);  // nodeElems*2 B

    size_t need = 237568ull + nodeElems * 2ull;
    int useConv = (ws_size >= need) ? 1 : 0;
    int convBlocks = useConv ? (int)((nodeElems + 2047ull) / 2048ull) : 0;

    prep_kernel<<<convBlocks + 449, 256, 0, stream>>>(
        nodeEmb, W_edge, W_k, W_v, W_o1, rel_emb, W_q, b_q,
        WTe, WTk, WTv, WTo1, Qtab, nodeBf16, convBlocks, nodeElems);

    int grid = (E + TE - 1) / TE;
    if (grid < 1) grid = 1;

    RelationAttentionMLPHead_10539849744626_kernel<<<grid, 512, 0, stream>>>(
        nodeEmb, nodeBf16, useConv, edgeIdx, relType, WTe, WTk, WTv, WTo1,
        b_edge, b_k, b_v, b_o1, W_o2, b_o2, Qtab, d_out, E);
}